// Round 6
// baseline (95.822 us; speedup 1.0000x reference)
//
#include <hip/hip_runtime.h>
#include <math.h>

#define TPB 256
#define NNEG 2048
#define D 128
#define CHUNK 64
#define NCH (NNEG / CHUNK)
#define RPB 128
#define RPW 32
#define L2E 1.44269504088896340736f

typedef __attribute__((ext_vector_type(8))) short bf16x8;
typedef __attribute__((ext_vector_type(4))) float f32x4;

#define MFMA16 __builtin_amdgcn_mfma_f32_16x16x32_bf16

static __device__ __forceinline__ unsigned int f2bf(float f) {
    unsigned int u = __float_as_uint(f);
    return (u + 0x7FFFu + ((u >> 16) & 1u)) >> 16;
}

static __device__ __forceinline__ void stage16(const void* g, void* l) {
    __builtin_amdgcn_global_load_lds(
        (const __attribute__((address_space(1))) unsigned int*)g,
        (__attribute__((address_space(3))) unsigned int*)l, 16, 0, 0);
}

// ---------------- prep: normalize negatives -> bf16 [NNEG][D], + log(samp_p) ----------------
__global__ __launch_bounds__(TPB) void sspe_prep(
    const float* __restrict__ embed,
    const float* __restrict__ sprobs,
    const int* __restrict__ sidx,
    unsigned int* __restrict__ en_bf,
    float* __restrict__ ln_samp)
{
    const int t = threadIdx.x;
    const int wave = t >> 6;
    const int lane = t & 63;
    const int j = blockIdx.x * 4 + wave;
    const int idx = sidx[j];

    float2 v = reinterpret_cast<const float2*>(embed)[(size_t)idx * 64 + lane];
    float ss = v.x * v.x + v.y * v.y;
    ss += __shfl_xor(ss, 1);
    ss += __shfl_xor(ss, 2);
    ss += __shfl_xor(ss, 4);
    ss += __shfl_xor(ss, 8);
    ss += __shfl_xor(ss, 16);
    ss += __shfl_xor(ss, 32);
    const float rinv = 1.0f / fmaxf(sqrtf(ss), 1e-12f);
    en_bf[(size_t)j * 64 + lane] = f2bf(v.x * rinv) | (f2bf(v.y * rinv) << 16);
    if (lane == 0) ln_samp[j] = logf(sprobs[idx] + 1e-10f);
}

// ---------------- main ----------------
__global__ __launch_bounds__(TPB, 2) void sspe_main(
    const float* __restrict__ hidden,
    const int* __restrict__ y,
    const float* __restrict__ embed,
    const float* __restrict__ sprobs,
    const int* __restrict__ sidx,
    const float* __restrict__ ltemp,
    const unsigned int* __restrict__ en_bf,
    const float* __restrict__ ln_samp,
    float2* __restrict__ partials)
{
    const int t = threadIdx.x;
    const int wave = t >> 6;
    const int lane = t & 63;
    const int rb = blockIdx.x * RPB;

    // 32 KB: prologue hidden tile (128 rows x 256B); afterwards two 16 KB B buffers
    __shared__ __align__(16) unsigned char smem[RPB * 256];
    __shared__ float pos_s[RPB];
    __shared__ int   ys[RPB];
    __shared__ float sums[RPB];
    __shared__ float2 red2[4];

    const float temp = __builtin_amdgcn_exp2f(fminf(ltemp[0], 4.6f) * L2E);
    const float t2 = temp * L2E;
    const float Mln = temp + 14.0f;     // uniform safe max (|cos|<=1, -log p <= 13.8)
    const float M2 = Mln * L2E;

    if (t < RPB) ys[t] = y[rb + t];
    __syncthreads();

    // ---- Prologue: normalize 32 rows/wave -> bf16 into smem (swizzled rows) ----
    #pragma unroll 1
    for (int i = 0; i < RPW; i += 4) {
        float2 h2[4], e2[4];
        int yi[4];
        #pragma unroll
        for (int u = 0; u < 4; ++u) {
            const int lr = wave * RPW + i + u;
            h2[u] = reinterpret_cast<const float2*>(hidden)[(size_t)(rb + lr) * 64 + lane];
            yi[u] = ys[lr];
        }
        #pragma unroll
        for (int u = 0; u < 4; ++u)
            e2[u] = reinterpret_cast<const float2*>(embed)[(size_t)yi[u] * 64 + lane];
        float ss[4], es[4], dt[4];
        #pragma unroll
        for (int u = 0; u < 4; ++u) {
            ss[u] = h2[u].x * h2[u].x + h2[u].y * h2[u].y;
            es[u] = e2[u].x * e2[u].x + e2[u].y * e2[u].y;
            dt[u] = h2[u].x * e2[u].x + h2[u].y * e2[u].y;
        }
        #pragma unroll
        for (int m = 1; m <= 32; m <<= 1)
            #pragma unroll
            for (int u = 0; u < 4; ++u) {
                ss[u] += __shfl_xor(ss[u], m);
                es[u] += __shfl_xor(es[u], m);
                dt[u] += __shfl_xor(dt[u], m);
            }
        #pragma unroll
        for (int u = 0; u < 4; ++u) {
            const int lr = wave * RPW + i + u;
            const float rinv = 1.0f / fmaxf(sqrtf(ss[u]), 1e-12f);
            const unsigned int uu = f2bf(h2[u].x * rinv) | (f2bf(h2[u].y * rinv) << 16);
            const int rx = (lr & 7) << 4;
            *reinterpret_cast<unsigned int*>(smem + lr * 256 + ((lane * 4) ^ rx)) = uu;
            if (lane == 0)
                pos_s[lr] = dt[u] * rinv * (1.0f / fmaxf(sqrtf(es[u]), 1e-12f)) * temp
                            - logf(sprobs[yi[u]] + 1e-10f);
        }
    }
    __syncthreads();

    // ---- A fragments: two 16-row tiles per wave ----
    bf16x8 A0[4], A1[4];
    {
        const int row0 = wave * RPW + (lane & 15);
        const int rx = (lane & 7) << 4;
        #pragma unroll
        for (int ks = 0; ks < 4; ++ks) {
            const int col = (ks * 64 + ((lane >> 4) << 4)) ^ rx;
            A0[ks] = *reinterpret_cast<const bf16x8*>(smem + row0 * 256 + col);
            A1[ks] = *reinterpret_cast<const bf16x8*>(smem + (row0 + 16) * 256 + col);
        }
    }
    __syncthreads();   // all A reads done before restaging over smem

    const int cj = lane & 15;
    const int rgrp = lane >> 4;
    int yv0[4], yv1[4];
    float l0[4], l1[4];
    #pragma unroll
    for (int j = 0; j < 4; ++j) {
        yv0[j] = ys[wave * RPW + rgrp * 4 + j];
        yv1[j] = ys[wave * RPW + 16 + rgrp * 4 + j];
        l0[j] = 0.0f;
        l1[j] = 0.0f;
    }

    // Fragment-order staging: region d = nt*4+ks holds, at byte L*16, the
    // fragment lane L reads for (nt,ks): en row (nt*16+(L&15)), bytes
    // ks*64 + (L>>4)*16. Per-lane GLOBAL source carries the permutation;
    // LDS dest stays linear (global_load_lds constraint).
    unsigned int soff[4];
    #pragma unroll
    for (int i = 0; i < 4; ++i) {
        const int d = wave * 4 + i;
        soff[i] = (unsigned int)((d >> 2) * 4096 + (lane & 15) * 256
                                 + (d & 3) * 64 + (lane >> 4) * 16);
    }
    const unsigned char* en = reinterpret_cast<const unsigned char*>(en_bf);

    // stage chunk 0 -> buffer 0
    #pragma unroll
    for (int i = 0; i < 4; ++i)
        stage16(en + soff[i], smem + (wave * 4 + i) * 1024);

    // ---- Main loop: 32 chunks, double-buffered, 1 barrier per chunk ----
    #pragma unroll 1
    for (int ch = 0; ch < NCH; ++ch) {
        const int cur = (ch & 1) << 14;
        __syncthreads();   // drains vmcnt: chunk ch staged

        float lk[4];
        int ci[4];
        #pragma unroll
        for (int nt = 0; nt < 4; ++nt) {
            lk[nt] = ln_samp[ch * 64 + nt * 16 + cj];
            ci[nt] = sidx[ch * 64 + nt * 16 + cj];
        }

        if (ch + 1 < NCH) {
            const unsigned char* enn = en + (size_t)(ch + 1) * 16384;
            #pragma unroll
            for (int i = 0; i < 4; ++i)
                stage16(enn + soff[i], smem + (cur ^ 16384) + (wave * 4 + i) * 1024);
        }

        const unsigned char* bb = smem + cur + lane * 16;
        f32x4 c0[4], c1[4];
        #pragma unroll
        for (int nt = 0; nt < 4; ++nt) {
            c0[nt] = (f32x4){0.f, 0.f, 0.f, 0.f};
            c1[nt] = (f32x4){0.f, 0.f, 0.f, 0.f};
            #pragma unroll
            for (int ks = 0; ks < 4; ++ks) {
                const bf16x8 b = *reinterpret_cast<const bf16x8*>(bb + (nt * 4 + ks) * 1024);
                c0[nt] = MFMA16(A0[ks], b, c0[nt], 0, 0, 0);
                c1[nt] = MFMA16(A1[ks], b, c1[nt], 0, 0, 0);
            }
        }

        #pragma unroll
        for (int nt = 0; nt < 4; ++nt) {
            const float nl2 = fmaf(lk[nt], -L2E, -M2);
            #pragma unroll
            for (int j = 0; j < 4; ++j) {
                const float a0 = fmaf(c0[nt][j], t2, nl2);
                const float a1 = fmaf(c1[nt][j], t2, nl2);
                const float e0 = __builtin_amdgcn_exp2f(a0);
                const float e1 = __builtin_amdgcn_exp2f(a1);
                l0[j] += (ci[nt] == yv0[j]) ? 0.0f : e0;
                l1[j] += (ci[nt] == yv1[j]) ? 0.0f : e1;
            }
        }
    }

    // ---- Reduce across the 16 neg-columns ----
    #pragma unroll
    for (int j = 0; j < 4; ++j) {
        float v0 = l0[j], v1 = l1[j];
        v0 += __shfl_xor(v0, 1);  v1 += __shfl_xor(v1, 1);
        v0 += __shfl_xor(v0, 2);  v1 += __shfl_xor(v1, 2);
        v0 += __shfl_xor(v0, 4);  v1 += __shfl_xor(v1, 4);
        v0 += __shfl_xor(v0, 8);  v1 += __shfl_xor(v1, 8);
        l0[j] = v0;
        l1[j] = v1;
    }
    if (cj == 0) {
        #pragma unroll
        for (int j = 0; j < 4; ++j) {
            sums[wave * RPW + rgrp * 4 + j] = l0[j];
            sums[wave * RPW + 16 + rgrp * 4 + j] = l1[j];
        }
    }
    __syncthreads();

    // ---- Per-row loss + block reduce ----
    float per = 0.0f, w = 0.0f;
    if (t < RPB) {
        const float s = sums[t];
        const float pa = pos_s[t];
        const float stot = s + __builtin_amdgcn_exp2f(fmaf(pa, L2E, -M2));
        w = (ys[t] != 0) ? 1.0f : 0.0f;
        per = (Mln + logf(stot) - pa) * w;
    }
    #pragma unroll
    for (int msk = 1; msk < 64; msk <<= 1) {
        per += __shfl_xor(per, msk);
        w += __shfl_xor(w, msk);
    }
    if (lane == 0) red2[wave] = make_float2(per, w);
    __syncthreads();
    if (t == 0) {
        const float2 a = red2[0], b = red2[1], c = red2[2], d = red2[3];
        partials[blockIdx.x] = make_float2(a.x + b.x + c.x + d.x,
                                           a.y + b.y + c.y + d.y);
    }
}

// ---------------- finalize: deterministic reduction ----------------
__global__ __launch_bounds__(TPB) void sspe_finalize(
    const float2* __restrict__ partials, int n, float* __restrict__ out)
{
    __shared__ float ssum[TPB];
    __shared__ float scnt[TPB];
    const int t = threadIdx.x;
    float s = 0.0f, c = 0.0f;
    for (int i = t; i < n; i += TPB) {
        const float2 p = partials[i];
        s += p.x; c += p.y;
    }
    ssum[t] = s; scnt[t] = c;
    __syncthreads();
    for (int k = TPB / 2; k > 0; k >>= 1) {
        if (t < k) { ssum[t] += ssum[t + k]; scnt[t] += scnt[t + k]; }
        __syncthreads();
    }
    if (t == 0) out[0] = ssum[0] / fmaxf(scnt[0], 1.0f);
}

extern "C" void kernel_launch(void* const* d_in, const int* in_sizes, int n_in,
                              void* d_out, int out_size, void* d_ws, size_t ws_size,
                              hipStream_t stream) {
    const float* hidden = (const float*)d_in[0];
    const int*   yv     = (const int*)d_in[1];
    const float* embed  = (const float*)d_in[2];
    const float* sprobs = (const float*)d_in[3];
    const int*   sidx   = (const int*)d_in[4];
    const float* ltemp  = (const float*)d_in[5];
    float* out = (float*)d_out;

    const int nrows = in_sizes[1];
    const int nblocks = nrows / RPB;   // 512

    char* w = (char*)d_ws;
    unsigned int* en_bf  = (unsigned int*)w;
    float*  ln_samp      = (float*)(w + (size_t)NNEG * D * 2);
    float2* partials     = (float2*)(w + (size_t)NNEG * D * 2 + NNEG * 4);

    sspe_prep<<<NNEG / 4, TPB, 0, stream>>>(embed, sprobs, sidx, en_bf, ln_samp);
    sspe_main<<<nblocks, TPB, 0, stream>>>(hidden, yv, embed, sprobs, sidx, ltemp,
                                           en_bf, ln_samp, partials);
    sspe_finalize<<<1, TPB, 0, stream>>>(partials, nblocks, out);
}

// Round 7
// 93.719 us; speedup vs baseline: 1.0224x; 1.0224x over previous
//
#include <hip/hip_runtime.h>
#include <math.h>

#define TPB 256
#define NNEG 2048
#define D 128
#define RPB 128            // rows per block
#define RPW 32             // rows per wave
#define NSPLIT 2           // negative-range splits across blocks
#define HALF (NNEG / NSPLIT)
#define NCHH (HALF / 64)   // 64-neg chunks per half
#define L2E 1.44269504088896340736f

typedef __attribute__((ext_vector_type(8))) short bf16x8;
typedef __attribute__((ext_vector_type(4))) float f32x4;

#define MFMA16 __builtin_amdgcn_mfma_f32_16x16x32_bf16

static __device__ __forceinline__ unsigned int f2bf(float f) {
    unsigned int u = __float_as_uint(f);
    return (u + 0x7FFFu + ((u >> 16) & 1u)) >> 16;
}

static __device__ __forceinline__ void stage16(const void* g, void* l) {
    __builtin_amdgcn_global_load_lds(
        (const __attribute__((address_space(1))) unsigned int*)g,
        (__attribute__((address_space(3))) unsigned int*)l, 16, 0, 0);
}

// ---------------- prep: normalize negatives -> bf16 [NNEG][D], + log(samp_p) ----------------
__global__ __launch_bounds__(TPB) void sspe_prep(
    const float* __restrict__ embed,
    const float* __restrict__ sprobs,
    const int* __restrict__ sidx,
    unsigned int* __restrict__ en_bf,
    float* __restrict__ ln_samp)
{
    const int t = threadIdx.x;
    const int wave = t >> 6;
    const int lane = t & 63;
    const int j = blockIdx.x * 4 + wave;
    const int idx = sidx[j];

    float2 v = reinterpret_cast<const float2*>(embed)[(size_t)idx * 64 + lane];
    float ss = v.x * v.x + v.y * v.y;
    ss += __shfl_xor(ss, 1);
    ss += __shfl_xor(ss, 2);
    ss += __shfl_xor(ss, 4);
    ss += __shfl_xor(ss, 8);
    ss += __shfl_xor(ss, 16);
    ss += __shfl_xor(ss, 32);
    const float rinv = 1.0f / fmaxf(sqrtf(ss), 1e-12f);
    en_bf[(size_t)j * 64 + lane] = f2bf(v.x * rinv) | (f2bf(v.y * rinv) << 16);
    if (lane == 0) ln_samp[j] = logf(sprobs[idx] + 1e-10f);
}

// ---------------- main: 128 rows x half the negatives per block ----------------
__global__ __launch_bounds__(TPB, 4) void sspe_main(
    const float* __restrict__ hidden,
    const int* __restrict__ y,
    const float* __restrict__ embed,
    const float* __restrict__ sprobs,
    const int* __restrict__ sidx,
    const float* __restrict__ ltemp,
    const unsigned int* __restrict__ en_bf,
    const float* __restrict__ ln_samp,
    float* __restrict__ pos_adj,   // [nrows]
    float* __restrict__ lsum,      // [NSPLIT][nrows]
    int nrows)
{
    const int t = threadIdx.x;
    const int wave = t >> 6;
    const int lane = t & 63;
    const int jh = blockIdx.x & 1;            // which negative half
    const int rb = (blockIdx.x >> 1) * RPB;   // row base

    // 32 KB: prologue hidden tile (128 rows x 256B) == two 16 KB B buffers later
    __shared__ __align__(16) unsigned char smem[RPB * 256];
    __shared__ int ys[RPB];

    const float temp = __builtin_amdgcn_exp2f(fminf(ltemp[0], 4.6f) * L2E);
    const float t2 = temp * L2E;
    const float Mln = temp + 14.0f;     // uniform safe max (|cos|<=1, -log p <= 13.8)
    const float M2 = Mln * L2E;

    if (t < RPB) ys[t] = y[rb + t];
    __syncthreads();

    // ---- Prologue: normalize 32 rows/wave -> bf16 into smem (swizzled rows) ----
    #pragma unroll 1
    for (int i = 0; i < RPW; i += 4) {
        float2 h2[4], e2[4];
        int yi[4];
        #pragma unroll
        for (int u = 0; u < 4; ++u) {
            const int lr = wave * RPW + i + u;
            h2[u] = reinterpret_cast<const float2*>(hidden)[(size_t)(rb + lr) * 64 + lane];
            yi[u] = ys[lr];
            e2[u] = make_float2(0.0f, 0.0f);
        }
        if (jh == 0) {
            #pragma unroll
            for (int u = 0; u < 4; ++u)
                e2[u] = reinterpret_cast<const float2*>(embed)[(size_t)yi[u] * 64 + lane];
        }
        float ss[4], es[4], dt[4];
        #pragma unroll
        for (int u = 0; u < 4; ++u) {
            ss[u] = h2[u].x * h2[u].x + h2[u].y * h2[u].y;
            es[u] = e2[u].x * e2[u].x + e2[u].y * e2[u].y;
            dt[u] = h2[u].x * e2[u].x + h2[u].y * e2[u].y;
        }
        #pragma unroll
        for (int m = 1; m <= 32; m <<= 1)
            #pragma unroll
            for (int u = 0; u < 4; ++u) {
                ss[u] += __shfl_xor(ss[u], m);
                es[u] += __shfl_xor(es[u], m);
                dt[u] += __shfl_xor(dt[u], m);
            }
        #pragma unroll
        for (int u = 0; u < 4; ++u) {
            const int lr = wave * RPW + i + u;
            const float rinv = 1.0f / fmaxf(sqrtf(ss[u]), 1e-12f);
            const unsigned int uu = f2bf(h2[u].x * rinv) | (f2bf(h2[u].y * rinv) << 16);
            const int rx = (lr & 7) << 4;
            *reinterpret_cast<unsigned int*>(smem + lr * 256 + ((lane * 4) ^ rx)) = uu;
            if (jh == 0 && lane == 0)
                pos_adj[rb + lr] = dt[u] * rinv * (1.0f / fmaxf(sqrtf(es[u]), 1e-12f)) * temp
                                   - logf(sprobs[yi[u]] + 1e-10f);
        }
    }
    __syncthreads();

    // ---- A fragments: two 16-row tiles per wave ----
    bf16x8 A0[4], A1[4];
    {
        const int row0 = wave * RPW + (lane & 15);
        const int rx = (lane & 7) << 4;
        #pragma unroll
        for (int ks = 0; ks < 4; ++ks) {
            const int col = (ks * 64 + ((lane >> 4) << 4)) ^ rx;
            A0[ks] = *reinterpret_cast<const bf16x8*>(smem + row0 * 256 + col);
            A1[ks] = *reinterpret_cast<const bf16x8*>(smem + (row0 + 16) * 256 + col);
        }
    }
    __syncthreads();   // all A reads done before restaging over smem

    const int cj = lane & 15;
    const int rgrp = lane >> 4;
    int yv0[4], yv1[4];
    float l0[4], l1[4];
    #pragma unroll
    for (int j = 0; j < 4; ++j) {
        yv0[j] = ys[wave * RPW + rgrp * 4 + j];
        yv1[j] = ys[wave * RPW + 16 + rgrp * 4 + j];
        l0[j] = 0.0f;
        l1[j] = 0.0f;
    }

    // Fragment-order staging (proven R6): region d = nt*4+ks holds, at byte
    // L*16, exactly the B fragment lane L consumes for (nt,ks). Per-lane
    // GLOBAL source carries the permutation; LDS dest stays linear.
    unsigned int soff[4];
    #pragma unroll
    for (int i = 0; i < 4; ++i) {
        const int d = wave * 4 + i;
        soff[i] = (unsigned int)((d >> 2) * 4096 + (lane & 15) * 256
                                 + (d & 3) * 64 + (lane >> 4) * 16);
    }
    const unsigned char* en = reinterpret_cast<const unsigned char*>(en_bf)
                            + (size_t)jh * HALF * 256;
    const int nb0 = jh * HALF;

    // stage chunk 0 -> buffer 0
    #pragma unroll
    for (int i = 0; i < 4; ++i)
        stage16(en + soff[i], smem + (wave * 4 + i) * 1024);

    // ---- Main loop: 16 chunks of 64 negs, double-buffered, 1 barrier/chunk ----
    #pragma unroll 1
    for (int ch = 0; ch < NCHH; ++ch) {
        const int cur = (ch & 1) << 14;
        __syncthreads();   // chunk ch staged

        float lk[4];
        int ci[4];
        #pragma unroll
        for (int nt = 0; nt < 4; ++nt) {
            lk[nt] = ln_samp[nb0 + ch * 64 + nt * 16 + cj];
            ci[nt] = sidx[nb0 + ch * 64 + nt * 16 + cj];
        }

        if (ch + 1 < NCHH) {
            const unsigned char* enn = en + (size_t)(ch + 1) * 16384;
            #pragma unroll
            for (int i = 0; i < 4; ++i)
                stage16(enn + soff[i], smem + (cur ^ 16384) + (wave * 4 + i) * 1024);
        }

        const unsigned char* bb = smem + cur + lane * 16;
        f32x4 c0[4], c1[4];
        #pragma unroll
        for (int nt = 0; nt < 4; ++nt) {
            c0[nt] = (f32x4){0.f, 0.f, 0.f, 0.f};
            c1[nt] = (f32x4){0.f, 0.f, 0.f, 0.f};
            #pragma unroll
            for (int ks = 0; ks < 4; ++ks) {
                const bf16x8 b = *reinterpret_cast<const bf16x8*>(bb + (nt * 4 + ks) * 1024);
                c0[nt] = MFMA16(A0[ks], b, c0[nt], 0, 0, 0);
                c1[nt] = MFMA16(A1[ks], b, c1[nt], 0, 0, 0);
            }
        }

        #pragma unroll
        for (int nt = 0; nt < 4; ++nt) {
            const float nl2 = fmaf(lk[nt], -L2E, -M2);
            #pragma unroll
            for (int j = 0; j < 4; ++j) {
                const float a0 = fmaf(c0[nt][j], t2, nl2);
                const float a1 = fmaf(c1[nt][j], t2, nl2);
                const float e0 = __builtin_amdgcn_exp2f(a0);
                const float e1 = __builtin_amdgcn_exp2f(a1);
                l0[j] += (ci[nt] == yv0[j]) ? 0.0f : e0;
                l1[j] += (ci[nt] == yv1[j]) ? 0.0f : e1;
            }
        }
    }

    // ---- Reduce across the 16 neg-columns; write per-row partial sums ----
    #pragma unroll
    for (int j = 0; j < 4; ++j) {
        float v0 = l0[j], v1 = l1[j];
        v0 += __shfl_xor(v0, 1);  v1 += __shfl_xor(v1, 1);
        v0 += __shfl_xor(v0, 2);  v1 += __shfl_xor(v1, 2);
        v0 += __shfl_xor(v0, 4);  v1 += __shfl_xor(v1, 4);
        v0 += __shfl_xor(v0, 8);  v1 += __shfl_xor(v1, 8);
        l0[j] = v0;
        l1[j] = v1;
    }
    if (cj == 0) {
        float* dst = lsum + (size_t)jh * nrows + rb + wave * RPW;
        #pragma unroll
        for (int j = 0; j < 4; ++j) {
            dst[rgrp * 4 + j] = l0[j];
            dst[16 + rgrp * 4 + j] = l1[j];
        }
    }
}

// ---------------- per-row loss combine + block partials ----------------
__global__ __launch_bounds__(TPB) void sspe_rows(
    const int* __restrict__ y,
    const float* __restrict__ ltemp,
    const float* __restrict__ pos_adj,
    const float* __restrict__ lsum,
    int nrows,
    float2* __restrict__ partials)
{
    __shared__ float2 red2[4];
    const int t = threadIdx.x;
    const int wave = t >> 6;
    const int lane = t & 63;
    const int r = blockIdx.x * TPB + t;

    const float temp = __builtin_amdgcn_exp2f(fminf(ltemp[0], 4.6f) * L2E);
    const float Mln = temp + 14.0f;
    const float M2 = Mln * L2E;

    const float s = lsum[r] + lsum[(size_t)nrows + r];
    const float pa = pos_adj[r];
    const float stot = s + __builtin_amdgcn_exp2f(fmaf(pa, L2E, -M2));
    float w = (y[r] != 0) ? 1.0f : 0.0f;
    float per = (Mln + logf(stot) - pa) * w;

    #pragma unroll
    for (int msk = 1; msk < 64; msk <<= 1) {
        per += __shfl_xor(per, msk);
        w += __shfl_xor(w, msk);
    }
    if (lane == 0) red2[wave] = make_float2(per, w);
    __syncthreads();
    if (t == 0) {
        const float2 a = red2[0], b = red2[1], c = red2[2], d = red2[3];
        partials[blockIdx.x] = make_float2(a.x + b.x + c.x + d.x,
                                           a.y + b.y + c.y + d.y);
    }
}

// ---------------- finalize: deterministic reduction ----------------
__global__ __launch_bounds__(TPB) void sspe_finalize(
    const float2* __restrict__ partials, int n, float* __restrict__ out)
{
    __shared__ float ssum[TPB];
    __shared__ float scnt[TPB];
    const int t = threadIdx.x;
    float s = 0.0f, c = 0.0f;
    for (int i = t; i < n; i += TPB) {
        const float2 p = partials[i];
        s += p.x; c += p.y;
    }
    ssum[t] = s; scnt[t] = c;
    __syncthreads();
    for (int k = TPB / 2; k > 0; k >>= 1) {
        if (t < k) { ssum[t] += ssum[t + k]; scnt[t] += scnt[t + k]; }
        __syncthreads();
    }
    if (t == 0) out[0] = ssum[0] / fmaxf(scnt[0], 1.0f);
}

extern "C" void kernel_launch(void* const* d_in, const int* in_sizes, int n_in,
                              void* d_out, int out_size, void* d_ws, size_t ws_size,
                              hipStream_t stream) {
    const float* hidden = (const float*)d_in[0];
    const int*   yv     = (const int*)d_in[1];
    const float* embed  = (const float*)d_in[2];
    const float* sprobs = (const float*)d_in[3];
    const int*   sidx   = (const int*)d_in[4];
    const float* ltemp  = (const float*)d_in[5];
    float* out = (float*)d_out;

    const int nrows = in_sizes[1];                 // 65536
    const int nblocks = (nrows / RPB) * NSPLIT;    // 1024

    char* w = (char*)d_ws;
    size_t off = 0;
    unsigned int* en_bf = (unsigned int*)(w + off); off += (size_t)NNEG * D * 2;   // 512 KB
    float* ln_samp      = (float*)(w + off);        off += (size_t)NNEG * 4;       // 8 KB
    float* pos_adj      = (float*)(w + off);        off += (size_t)nrows * 4;      // 256 KB
    float* lsum         = (float*)(w + off);        off += (size_t)NSPLIT * nrows * 4; // 512 KB
    float2* partials    = (float2*)(w + off);

    sspe_prep<<<NNEG / 4, TPB, 0, stream>>>(embed, sprobs, sidx, en_bf, ln_samp);
    sspe_main<<<nblocks, TPB, 0, stream>>>(hidden, yv, embed, sprobs, sidx, ltemp,
                                           en_bf, ln_samp, pos_adj, lsum, nrows);
    sspe_rows<<<nrows / TPB, TPB, 0, stream>>>(yv, ltemp, pos_adj, lsum, nrows, partials);
    sspe_finalize<<<1, TPB, 0, stream>>>(partials, nrows / TPB, out);
}